// Round 1
// baseline (404.554 us; speedup 1.0000x reference)
//
#include <hip/hip_runtime.h>

typedef unsigned int uint;

#define BATCH   8192
#define DIM     128
#define TMARGIN 0.3f
#define FMAX_BITS 0x7F7FFFFFu
#define BIGF 3.402823466e+38f

// ---------------- kernel 1: row squared norms + init min arrays --------------
__global__ __launch_bounds__(256) void k_norms_init(
    const float* __restrict__ emb, float* __restrict__ norms,
    uint* __restrict__ negmin, uint* __restrict__ semimin) {
  int w = threadIdx.x >> 6, lane = threadIdx.x & 63;
  int row = blockIdx.x * 4 + w;
  float2 v = reinterpret_cast<const float2*>(emb + (size_t)row * DIM)[lane];
  float s = v.x * v.x + v.y * v.y;
  #pragma unroll
  for (int off = 32; off; off >>= 1) s += __shfl_xor(s, off);
  if (lane == 0) {
    norms[row]   = s;
    negmin[row]  = FMAX_BITS;
    semimin[row] = FMAX_BITS;
  }
}

// ---------------- kernel 2: hardest positive per row (same-class only) -------
// one wave per row; lanes stride over j; only same-class pairs compute the dot.
__global__ __launch_bounds__(256) void k_hardest_pos(
    const float* __restrict__ emb, const int* __restrict__ labels,
    const float* __restrict__ norms, float* __restrict__ hp) {
  __shared__ float ei[4][DIM];
  int w = threadIdx.x >> 6, lane = threadIdx.x & 63;
  int row = blockIdx.x * 4 + w;
  float2 v = reinterpret_cast<const float2*>(emb + (size_t)row * DIM)[lane];
  ei[w][2 * lane]     = v.x;
  ei[w][2 * lane + 1] = v.y;
  __syncthreads();
  int lbl  = labels[row];
  float ni = norms[row];
  float m  = 0.f;   // init 0 (ref uses -1; differs only for invalid rows)
  for (int j = lane; j < BATCH; j += 64) {
    if (labels[j] == lbl && j != row) {
      const float4* ej = reinterpret_cast<const float4*>(emb + (size_t)j * DIM);
      float dot = 0.f;
      #pragma unroll
      for (int k = 0; k < DIM / 4; ++k) {
        float4 x = ej[k];
        dot += ei[w][4*k]   * x.x + ei[w][4*k+1] * x.y
             + ei[w][4*k+2] * x.z + ei[w][4*k+3] * x.w;
      }
      float sq   = fmaxf(ni + norms[j] - 2.f * dot, 0.f);
      float dist = sq > 0.f ? sqrtf(sq) : 0.f;
      m = fmaxf(m, dist);
    }
  }
  #pragma unroll
  for (int off = 32; off; off >>= 1) m = fmaxf(m, __shfl_xor(m, off));
  if (lane == 0) hp[row] = m;
}

// ---------------- kernel 3: fused Gram tile + masked row reductions ----------
#define TM 128
#define TN 128
#define KC 32
#define LDSS 132   // k-major row stride (words); 16B-aligned, breaks pow2 banks

__global__ __launch_bounds__(256) void k_main(
    const float* __restrict__ emb, const int* __restrict__ labels,
    const float* __restrict__ norms, const float* __restrict__ hp,
    uint* __restrict__ negmin, uint* __restrict__ semimin) {
  __shared__ float As[KC * LDSS];
  __shared__ float Bs[KC * LDSS];
  const int t  = threadIdx.x;
  const int tm = t >> 4, tn = t & 15;
  const int i0 = blockIdx.y * TM;
  const int j0 = blockIdx.x * TN;

  float acc[8][8];
  #pragma unroll
  for (int r = 0; r < 8; ++r)
    #pragma unroll
    for (int c = 0; c < 8; ++c) acc[r][c] = 0.f;

  for (int kt = 0; kt < DIM; kt += KC) {
    if (kt) __syncthreads();
    // stage A,B chunks (128 rows x 32 k) transposed into k-major LDS
    #pragma unroll
    for (int s = 0; s < 4; ++s) {
      int f   = t + 256 * s;
      int row = f >> 3;
      int c4  = (f & 7) << 2;
      float4 x = *reinterpret_cast<const float4*>(emb + (size_t)(i0 + row) * DIM + kt + c4);
      As[(c4+0)*LDSS + row] = x.x;
      As[(c4+1)*LDSS + row] = x.y;
      As[(c4+2)*LDSS + row] = x.z;
      As[(c4+3)*LDSS + row] = x.w;
      float4 y = *reinterpret_cast<const float4*>(emb + (size_t)(j0 + row) * DIM + kt + c4);
      Bs[(c4+0)*LDSS + row] = y.x;
      Bs[(c4+1)*LDSS + row] = y.y;
      Bs[(c4+2)*LDSS + row] = y.z;
      Bs[(c4+3)*LDSS + row] = y.w;
    }
    __syncthreads();
    #pragma unroll
    for (int k = 0; k < KC; ++k) {
      const float* ap = &As[k * LDSS];
      const float* bp = &Bs[k * LDSS];
      float4 alo = *reinterpret_cast<const float4*>(ap + 4 * tm);
      float4 ahi = *reinterpret_cast<const float4*>(ap + 64 + 4 * tm);
      float4 blo = *reinterpret_cast<const float4*>(bp + 4 * tn);
      float4 bhi = *reinterpret_cast<const float4*>(bp + 64 + 4 * tn);
      float a[8] = {alo.x, alo.y, alo.z, alo.w, ahi.x, ahi.y, ahi.z, ahi.w};
      float b[8] = {blo.x, blo.y, blo.z, blo.w, bhi.x, bhi.y, bhi.z, bhi.w};
      #pragma unroll
      for (int r = 0; r < 8; ++r)
        #pragma unroll
        for (int c = 0; c < 8; ++c)
          acc[r][c] = fmaf(a[r], b[c], acc[r][c]);
    }
  }

  // epilogue: dist + masks + per-row min, reduce across the 16 col-threads
  int ro[8], co[8];
  #pragma unroll
  for (int r = 0; r < 4; ++r) { ro[r] = 4*tm + r; ro[r+4] = 64 + 4*tm + r; }
  #pragma unroll
  for (int c = 0; c < 4; ++c) { co[c] = 4*tn + c; co[c+4] = 64 + 4*tn + c; }

  float ni[8], hpi[8], nj[8];
  int li[8], lj[8];
  #pragma unroll
  for (int r = 0; r < 8; ++r) {
    ni[r]  = norms[i0 + ro[r]];
    hpi[r] = hp[i0 + ro[r]];
    li[r]  = labels[i0 + ro[r]];
  }
  #pragma unroll
  for (int c = 0; c < 8; ++c) {
    nj[c] = norms[j0 + co[c]];
    lj[c] = labels[j0 + co[c]];
  }

  #pragma unroll
  for (int r = 0; r < 8; ++r) {
    float rn = BIGF, rs = BIGF;
    float h = hpi[r], thr = h + TMARGIN;
    #pragma unroll
    for (int c = 0; c < 8; ++c) {
      float sq   = fmaxf(ni[r] + nj[c] - 2.f * acc[r][c], 0.f);
      float dist = sq > 0.f ? sqrtf(sq) : 0.f;
      if (li[r] != lj[c]) {
        rn = fminf(rn, dist);
        if (dist > h && dist < thr) rs = fminf(rs, dist);
      }
    }
    #pragma unroll
    for (int off = 1; off < 16; off <<= 1) {
      rn = fminf(rn, __shfl_xor(rn, off));
      rs = fminf(rs, __shfl_xor(rs, off));
    }
    if (tn == 0) {
      atomicMin(negmin  + i0 + ro[r], __float_as_uint(rn));
      atomicMin(semimin + i0 + ro[r], __float_as_uint(rs));
    }
  }
}

// ---------------- kernel 4: finalize scalar ----------------------------------
__global__ __launch_bounds__(256) void k_final(
    const float* __restrict__ hp, const uint* __restrict__ negmin,
    const uint* __restrict__ semimin, float* __restrict__ out) {
  float total = 0.f, count = 0.f;
  for (int i = threadIdx.x; i < BATCH; i += 256) {
    float h = hp[i];
    uint nu = negmin[i], su = semimin[i];
    float sn = (su != FMAX_BITS) ? __uint_as_float(su) : __uint_as_float(nu);
    if (h > 0.f && nu != FMAX_BITS) {
      total += fmaxf(h - sn + TMARGIN, 0.f);
      count += 1.f;
    }
  }
  #pragma unroll
  for (int off = 32; off; off >>= 1) {
    total += __shfl_xor(total, off);
    count += __shfl_xor(count, off);
  }
  __shared__ float st[4], sc[4];
  int w = threadIdx.x >> 6, lane = threadIdx.x & 63;
  if (lane == 0) { st[w] = total; sc[w] = count; }
  __syncthreads();
  if (threadIdx.x == 0) {
    float T = st[0] + st[1] + st[2] + st[3];
    float C = sc[0] + sc[1] + sc[2] + sc[3];
    out[0] = C > 0.f ? T / C : 0.f;
  }
}

extern "C" void kernel_launch(void* const* d_in, const int* in_sizes, int n_in,
                              void* d_out, int out_size, void* d_ws, size_t ws_size,
                              hipStream_t stream) {
  const float* emb   = (const float*)d_in[0];
  const int* labels  = (const int*)d_in[1];
  float* out         = (float*)d_out;

  float* norms  = (float*)d_ws;            // 8192 f32
  float* hp     = norms + BATCH;           // 8192 f32
  uint* negmin  = (uint*)(hp + BATCH);     // 8192 u32
  uint* semimin = negmin + BATCH;          // 8192 u32

  k_norms_init<<<BATCH / 4, 256, 0, stream>>>(emb, norms, negmin, semimin);
  k_hardest_pos<<<BATCH / 4, 256, 0, stream>>>(emb, labels, norms, hp);
  k_main<<<dim3(BATCH / TN, BATCH / TM), 256, 0, stream>>>(emb, labels, norms, hp,
                                                           negmin, semimin);
  k_final<<<1, 256, 0, stream>>>(hp, negmin, semimin, out);
}

// Round 2
// 362.846 us; speedup vs baseline: 1.1149x; 1.1149x over previous
//
#include <hip/hip_runtime.h>

typedef unsigned int uint;
typedef _Float16 half4 __attribute__((ext_vector_type(4)));
typedef _Float16 half8 __attribute__((ext_vector_type(8)));
typedef float f32x4 __attribute__((ext_vector_type(4)));

#define BATCH   8192
#define DIM     128
#define NCLS    512
#define TMARGIN 0.3f
#define FMAX_BITS 0x7F7FFFFFu
#define BIGF 3.402823466e+38f
#define MAXM 768

// ---------------- kernel 1: row squared norms + init min arrays --------------
__global__ __launch_bounds__(256) void k_norms_init(
    const float* __restrict__ emb, float* __restrict__ norms,
    uint* __restrict__ negmin, uint* __restrict__ semimin) {
  int w = threadIdx.x >> 6, lane = threadIdx.x & 63;
  int row = blockIdx.x * 4 + w;
  float2 v = reinterpret_cast<const float2*>(emb + (size_t)row * DIM)[lane];
  float s = v.x * v.x + v.y * v.y;
  #pragma unroll
  for (int off = 32; off; off >>= 1) s += __shfl_xor(s, off);
  if (lane == 0) {
    norms[row]   = s;
    negmin[row]  = FMAX_BITS;
    semimin[row] = FMAX_BITS;
  }
}

// ---------------- kernel 2: fp32 -> f16 hi/lo split ---------------------------
__global__ __launch_bounds__(256) void k_split(
    const float* __restrict__ emb, _Float16* __restrict__ eh,
    _Float16* __restrict__ el) {
  int i = blockIdx.x * 256 + threadIdx.x;   // one float4 per thread
  float4 x = reinterpret_cast<const float4*>(emb)[i];
  _Float16 h0 = (_Float16)x.x, h1 = (_Float16)x.y,
           h2 = (_Float16)x.z, h3 = (_Float16)x.w;
  half4 hv = {h0, h1, h2, h3};
  half4 lv = {(_Float16)(x.x - (float)h0), (_Float16)(x.y - (float)h1),
              (_Float16)(x.z - (float)h2), (_Float16)(x.w - (float)h3)};
  reinterpret_cast<half4*>(eh)[i] = hv;
  reinterpret_cast<half4*>(el)[i] = lv;
}

// ---------------- kernel 3: hardest positive, one block per class ------------
__global__ __launch_bounds__(256) void k_hp(
    const float* __restrict__ emb, const int* __restrict__ labels,
    const float* __restrict__ norms, float* __restrict__ hp) {
  __shared__ int members[MAXM];
  __shared__ int cnt;
  int c = blockIdx.x;
  if (threadIdx.x == 0) cnt = 0;
  __syncthreads();
  for (int i = threadIdx.x; i < BATCH; i += 256)
    if (labels[i] == c) {
      int p = atomicAdd(&cnt, 1);
      if (p < MAXM) members[p] = i;
    }
  __syncthreads();
  int m = cnt < MAXM ? cnt : MAXM;
  int w = threadIdx.x >> 6, lane = threadIdx.x & 63;
  for (int a = w; a < m; a += 4) {
    int i = members[a];
    float2 ei = reinterpret_cast<const float2*>(emb + (size_t)i * DIM)[lane];
    float ni = norms[i];
    float best = 0.f;                       // squared-distance max
    for (int b = 0; b < m; ++b) {
      if (b == a) continue;
      int j = members[b];
      float2 ej = reinterpret_cast<const float2*>(emb + (size_t)j * DIM)[lane];
      float d = ei.x * ej.x + ei.y * ej.y;
      #pragma unroll
      for (int off = 32; off; off >>= 1) d += __shfl_xor(d, off);
      float sq = fmaxf(ni + norms[j] - 2.f * d, 0.f);
      best = fmaxf(best, sq);
    }
    if (lane == 0) hp[i] = best > 0.f ? sqrtf(best) : 0.f;
  }
}

// ---------------- kernel 4: MFMA Gram + masked row mins (squared space) ------
// 128x128 tile per block, 4 waves, each wave 64x64 via 4x4 frags of 16x16x32.
// A,B fragments load straight from global (L2-resident); no LDS, no barriers.
__global__ __launch_bounds__(256) void k_main(
    const _Float16* __restrict__ eh, const _Float16* __restrict__ el,
    const int* __restrict__ labels, const float* __restrict__ norms,
    const float* __restrict__ hp,
    uint* __restrict__ negmin, uint* __restrict__ semimin) {
  const int t = threadIdx.x;
  const int lane = t & 63, w = t >> 6;
  const int wr = w >> 1, wc = w & 1;
  const int i0 = blockIdx.y * 128 + wr * 64;
  const int j0 = blockIdx.x * 128 + wc * 64;
  const int r16 = lane & 15;   // row (A) / col (B) within fragment
  const int kg  = lane >> 4;   // k-group 0..3

  const half8* __restrict__ peh = reinterpret_cast<const half8*>(eh);
  const half8* __restrict__ pel = reinterpret_cast<const half8*>(el);
  // half8 index for row r, kstep ks: r*16 + 4*ks + kg
  int ra[4], rb[4];
  #pragma unroll
  for (int m = 0; m < 4; ++m) ra[m] = (i0 + 16 * m + r16) * 16 + kg;
  #pragma unroll
  for (int n = 0; n < 4; ++n) rb[n] = (j0 + 16 * n + r16) * 16 + kg;

  f32x4 acc[4][4];
  #pragma unroll
  for (int m = 0; m < 4; ++m)
    #pragma unroll
    for (int n = 0; n < 4; ++n) acc[m][n] = (f32x4){0.f, 0.f, 0.f, 0.f};

  #pragma unroll
  for (int ks = 0; ks < 4; ++ks) {
    half8 ah[4], al[4], bh[4], bl[4];
    #pragma unroll
    for (int m = 0; m < 4; ++m) {
      ah[m] = peh[ra[m] + 4 * ks];
      al[m] = pel[ra[m] + 4 * ks];
    }
    #pragma unroll
    for (int n = 0; n < 4; ++n) {
      bh[n] = peh[rb[n] + 4 * ks];
      bl[n] = pel[rb[n] + 4 * ks];
    }
    #pragma unroll
    for (int m = 0; m < 4; ++m)
      #pragma unroll
      for (int n = 0; n < 4; ++n) {
        acc[m][n] = __builtin_amdgcn_mfma_f32_16x16x32_f16(ah[m], bh[n], acc[m][n], 0, 0, 0);
        acc[m][n] = __builtin_amdgcn_mfma_f32_16x16x32_f16(ah[m], bl[n], acc[m][n], 0, 0, 0);
        acc[m][n] = __builtin_amdgcn_mfma_f32_16x16x32_f16(al[m], bh[n], acc[m][n], 0, 0, 0);
      }
  }

  // epilogue in squared-distance space; C/D layout: col=lane&15, row=kg*4+reg
  float nj[4];
  int lj[4];
  #pragma unroll
  for (int n = 0; n < 4; ++n) {
    int gj = j0 + 16 * n + r16;
    nj[n] = norms[gj];
    lj[n] = labels[gj];
  }
  #pragma unroll
  for (int m = 0; m < 4; ++m) {
    #pragma unroll
    for (int q = 0; q < 4; ++q) {
      int gi = i0 + 16 * m + kg * 4 + q;
      float ni  = norms[gi];
      int   li  = labels[gi];
      float h   = hp[gi];
      float hsq = h * h;
      float hs2 = (h + TMARGIN) * (h + TMARGIN);
      float rn = BIGF, rs = BIGF;
      #pragma unroll
      for (int n = 0; n < 4; ++n) {
        float sq = fmaxf(ni + nj[n] - 2.f * acc[m][n][q], 0.f);
        if (li != lj[n]) {
          rn = fminf(rn, sq);
          if (sq > hsq && sq < hs2) rs = fminf(rs, sq);
        }
      }
      #pragma unroll
      for (int off = 1; off < 16; off <<= 1) {
        rn = fminf(rn, __shfl_xor(rn, off));
        rs = fminf(rs, __shfl_xor(rs, off));
      }
      if (r16 == 0) {
        atomicMin(negmin  + gi, __float_as_uint(rn));
        atomicMin(semimin + gi, __float_as_uint(rs));
      }
    }
  }
}

// ---------------- kernel 5: finalize scalar ----------------------------------
__global__ __launch_bounds__(256) void k_final(
    const float* __restrict__ hp, const uint* __restrict__ negmin,
    const uint* __restrict__ semimin, float* __restrict__ out) {
  float total = 0.f, count = 0.f;
  for (int i = threadIdx.x; i < BATCH; i += 256) {
    float h = hp[i];
    uint nu = negmin[i], su = semimin[i];
    float snsq = (su != FMAX_BITS) ? __uint_as_float(su) : __uint_as_float(nu);
    if (h > 0.f && nu != FMAX_BITS) {
      total += fmaxf(h - sqrtf(snsq) + TMARGIN, 0.f);
      count += 1.f;
    }
  }
  #pragma unroll
  for (int off = 32; off; off >>= 1) {
    total += __shfl_xor(total, off);
    count += __shfl_xor(count, off);
  }
  __shared__ float st[4], sc[4];
  int w = threadIdx.x >> 6, lane = threadIdx.x & 63;
  if (lane == 0) { st[w] = total; sc[w] = count; }
  __syncthreads();
  if (threadIdx.x == 0) {
    float T = st[0] + st[1] + st[2] + st[3];
    float C = sc[0] + sc[1] + sc[2] + sc[3];
    out[0] = C > 0.f ? T / C : 0.f;
  }
}

extern "C" void kernel_launch(void* const* d_in, const int* in_sizes, int n_in,
                              void* d_out, int out_size, void* d_ws, size_t ws_size,
                              hipStream_t stream) {
  const float* emb  = (const float*)d_in[0];
  const int* labels = (const int*)d_in[1];
  float* out        = (float*)d_out;

  // workspace layout (16B-aligned pieces)
  _Float16* eh  = (_Float16*)d_ws;                    // 8192*128 f16 = 2 MB
  _Float16* el  = eh + (size_t)BATCH * DIM;           // 2 MB
  float* norms  = (float*)(el + (size_t)BATCH * DIM); // 32 KB
  float* hp     = norms + BATCH;                      // 32 KB
  uint* negmin  = (uint*)(hp + BATCH);                // 32 KB
  uint* semimin = negmin + BATCH;                     // 32 KB

  k_norms_init<<<BATCH / 4, 256, 0, stream>>>(emb, norms, negmin, semimin);
  k_split<<<(BATCH * DIM / 4) / 256, 256, 0, stream>>>(emb, eh, el);
  k_hp<<<NCLS, 256, 0, stream>>>(emb, labels, norms, hp);
  k_main<<<dim3(BATCH / 128, BATCH / 128), 256, 0, stream>>>(eh, el, labels, norms, hp,
                                                             negmin, semimin);
  k_final<<<1, 256, 0, stream>>>(hp, negmin, semimin, out);
}

// Round 3
// 222.840 us; speedup vs baseline: 1.8154x; 1.6283x over previous
//
#include <hip/hip_runtime.h>

typedef unsigned int uint;
typedef _Float16 half2v __attribute__((ext_vector_type(2)));
typedef _Float16 half8  __attribute__((ext_vector_type(8)));
typedef float    f32x4  __attribute__((ext_vector_type(4)));

#define BATCH   8192
#define DIM     128
#define NCLS    512
#define TMARGIN 0.3f
#define FMAX_BITS 0x7F7FFFFFu
#define BIGF 3.402823466e+38f
#define MAXM 128

// ---------- k_prep: norms + f16 hi/lo split + init mins + class scatter ------
__global__ __launch_bounds__(256) void k_prep(
    const float* __restrict__ emb, const int* __restrict__ labels,
    _Float16* __restrict__ eh, _Float16* __restrict__ el,
    float* __restrict__ norms, uint* __restrict__ negmin, uint* __restrict__ semimin,
    int* __restrict__ counts, int* __restrict__ members) {
  int w = threadIdx.x >> 6, lane = threadIdx.x & 63;
  int row = blockIdx.x * 4 + w;
  float2 v = reinterpret_cast<const float2*>(emb + (size_t)row * DIM)[lane];
  _Float16 h0 = (_Float16)v.x, h1 = (_Float16)v.y;
  half2v hv = {h0, h1};
  half2v lv = {(_Float16)(v.x - (float)h0), (_Float16)(v.y - (float)h1)};
  reinterpret_cast<half2v*>(eh + (size_t)row * DIM)[lane] = hv;
  reinterpret_cast<half2v*>(el + (size_t)row * DIM)[lane] = lv;
  float s = v.x * v.x + v.y * v.y;
  #pragma unroll
  for (int off = 32; off; off >>= 1) s += __shfl_xor(s, off);
  if (lane == 0) {
    norms[row]   = s;
    negmin[row]  = FMAX_BITS;
    semimin[row] = FMAX_BITS;
    int c = labels[row];
    int p = atomicAdd(&counts[c], 1);
    if (p < MAXM) members[c * MAXM + p] = row;
  }
}

// ---------- k_hp: hardest positive per row, from member lists ----------------
__global__ __launch_bounds__(256) void k_hp(
    const float* __restrict__ emb, const float* __restrict__ norms,
    const int* __restrict__ counts, const int* __restrict__ members,
    float* __restrict__ hp) {
  int c = blockIdx.x;
  int m = counts[c]; if (m > MAXM) m = MAXM;
  int w = threadIdx.x >> 6, lane = threadIdx.x & 63;
  for (int a = w; a < m; a += 4) {
    int i = members[c * MAXM + a];
    float2 ei = reinterpret_cast<const float2*>(emb + (size_t)i * DIM)[lane];
    float ni = norms[i];
    float best = 0.f;                      // squared-space max
    for (int b = 0; b < m; ++b) {
      if (b == a) continue;
      int j = members[c * MAXM + b];
      float2 ej = reinterpret_cast<const float2*>(emb + (size_t)j * DIM)[lane];
      float d = ei.x * ej.x + ei.y * ej.y;
      #pragma unroll
      for (int off = 32; off; off >>= 1) d += __shfl_xor(d, off);
      float sq = fmaxf(ni + norms[j] - 2.f * d, 0.f);
      best = fmaxf(best, sq);
    }
    if (lane == 0) hp[i] = best > 0.f ? sqrtf(best) : 0.f;
  }
}

// ---------- k_main: LDS-pipelined MFMA Gram (symmetric) + masked mins --------
// 128x128 tile, 4 waves (2x2), wave tile 64x64 = 4x4 frags of 16x16x32 f16.
// K=128 in 4 chunks of 32. LDS sections: 0:Ah 1:Al 2:Bh 3:Bl, each [128][4]x16B,
// kblk XOR-swizzled by row&3. Only bx>=by blocks run; off-diag emit row+col mins.
__global__ __launch_bounds__(256, 2) void k_main(
    const _Float16* __restrict__ eh, const _Float16* __restrict__ el,
    const int* __restrict__ labels, const float* __restrict__ norms,
    const float* __restrict__ hp,
    uint* __restrict__ negmin, uint* __restrict__ semimin) {
  const int bx = blockIdx.x, by = blockIdx.y;
  if (bx < by) return;
  __shared__ __align__(16) char lds[32768];
  const int t = threadIdx.x, lane = t & 63, w = t >> 6;
  const int wr = w >> 1, wc = w & 1;
  const int i0 = by * 128, j0 = bx * 128;
  const int r16 = lane & 15, kg = lane >> 4;

  half8 streg[8];
  auto load_chunk = [&](int c) {
    #pragma unroll
    for (int i = 0; i < 8; ++i) {
      int vdx = ((i & 1) << 8) + t;          // 0..511 within section
      int row = vdx >> 2, kblk = vdx & 3;
      int s = i >> 1;                        // 0:Ah 1:Al 2:Bh 3:Bl
      const _Float16* base = (s == 0 || s == 2) ? eh : el;
      int rb = (s < 2) ? i0 : j0;
      streg[i] = *reinterpret_cast<const half8*>(
          base + (size_t)(rb + row) * DIM + c * 32 + kblk * 8);
    }
  };
  auto write_chunk = [&]() {
    #pragma unroll
    for (int i = 0; i < 8; ++i) {
      int vdx = ((i & 1) << 8) + t;
      int row = vdx >> 2, kblk = vdx & 3;
      int s = i >> 1;
      int off = s * 8192 + row * 64 + ((kblk ^ (row & 3)) << 4);
      *reinterpret_cast<half8*>(lds + off) = streg[i];
    }
  };

  f32x4 acc[4][4];
  #pragma unroll
  for (int m = 0; m < 4; ++m)
    #pragma unroll
    for (int n = 0; n < 4; ++n) acc[m][n] = (f32x4){0.f, 0.f, 0.f, 0.f};

  load_chunk(0);
  #pragma unroll
  for (int c = 0; c < 4; ++c) {
    __syncthreads();                 // prev compute done; also drains loads(c)
    write_chunk();
    __syncthreads();                 // staged data visible
    if (c < 3) load_chunk(c + 1);    // in flight under compute(c)
    half8 ah[4], al[4], bh[4], bl[4];
    #pragma unroll
    for (int m = 0; m < 4; ++m) {
      int row = wr * 64 + 16 * m + r16;
      int sl = (kg ^ (row & 3)) << 4;
      ah[m] = *reinterpret_cast<const half8*>(lds +        row * 64 + sl);
      al[m] = *reinterpret_cast<const half8*>(lds + 8192 + row * 64 + sl);
    }
    #pragma unroll
    for (int n = 0; n < 4; ++n) {
      int row = wc * 64 + 16 * n + r16;
      int sl = (kg ^ (row & 3)) << 4;
      bh[n] = *reinterpret_cast<const half8*>(lds + 16384 + row * 64 + sl);
      bl[n] = *reinterpret_cast<const half8*>(lds + 24576 + row * 64 + sl);
    }
    #pragma unroll
    for (int m = 0; m < 4; ++m)
      #pragma unroll
      for (int n = 0; n < 4; ++n) {
        acc[m][n] = __builtin_amdgcn_mfma_f32_16x16x32_f16(ah[m], bh[n], acc[m][n], 0, 0, 0);
        acc[m][n] = __builtin_amdgcn_mfma_f32_16x16x32_f16(ah[m], bl[n], acc[m][n], 0, 0, 0);
        acc[m][n] = __builtin_amdgcn_mfma_f32_16x16x32_f16(al[m], bh[n], acc[m][n], 0, 0, 0);
      }
  }

  // ---- epilogue, squared-distance space. C/D: col=r16, row=4*kg+reg ----
  const int i0w = i0 + wr * 64, j0w = j0 + wc * 64;
  float nj[4], hsqj[4], hs2j[4];
  int lj[4];
  #pragma unroll
  for (int n = 0; n < 4; ++n) {
    int gj = j0w + 16 * n + r16;
    nj[n] = norms[gj];
    lj[n] = labels[gj];
    float hj = hp[gj];
    hsqj[n] = hj * hj;
    hs2j[n] = (hj + TMARGIN) * (hj + TMARGIN);
  }
  int liv[16];
  #pragma unroll
  for (int m = 0; m < 4; ++m) {
    #pragma unroll
    for (int q = 0; q < 4; ++q) {
      int gi = i0w + 16 * m + 4 * kg + q;
      float ni = norms[gi];
      int li = labels[gi];
      liv[m * 4 + q] = li;
      float h = hp[gi];
      float hsq = h * h, hs2 = (h + TMARGIN) * (h + TMARGIN);
      float rn = BIGF, rs = BIGF;
      #pragma unroll
      for (int n = 0; n < 4; ++n) {
        float sq = fmaxf(ni + nj[n] - 2.f * acc[m][n][q], 0.f);
        acc[m][n][q] = sq;              // keep for col pass
        if (li != lj[n]) {
          rn = fminf(rn, sq);
          if (sq > hsq && sq < hs2) rs = fminf(rs, sq);
        }
      }
      #pragma unroll
      for (int off = 1; off < 16; off <<= 1) {
        rn = fminf(rn, __shfl_xor(rn, off));
        rs = fminf(rs, __shfl_xor(rs, off));
      }
      if (r16 == 0) {
        atomicMin(negmin  + gi, __float_as_uint(rn));
        atomicMin(semimin + gi, __float_as_uint(rs));
      }
    }
  }
  if (bx != by) {                       // col pass: pairs (gj, gi)
    #pragma unroll
    for (int n = 0; n < 4; ++n) {
      float rn = BIGF, rs = BIGF;
      #pragma unroll
      for (int m = 0; m < 4; ++m)
        #pragma unroll
        for (int q = 0; q < 4; ++q) {
          float sq = acc[m][n][q];
          if (liv[m * 4 + q] != lj[n]) {
            rn = fminf(rn, sq);
            if (sq > hsqj[n] && sq < hs2j[n]) rs = fminf(rs, sq);
          }
        }
      rn = fminf(rn, __shfl_xor(rn, 16));
      rs = fminf(rs, __shfl_xor(rs, 16));
      rn = fminf(rn, __shfl_xor(rn, 32));
      rs = fminf(rs, __shfl_xor(rs, 32));
      if (kg == 0) {
        int gj = j0w + 16 * n + r16;
        atomicMin(negmin  + gj, __float_as_uint(rn));
        atomicMin(semimin + gj, __float_as_uint(rs));
      }
    }
  }
}

// ---------- k_final ------------------------------------------------------------
__global__ __launch_bounds__(256) void k_final(
    const float* __restrict__ hp, const uint* __restrict__ negmin,
    const uint* __restrict__ semimin, float* __restrict__ out) {
  float total = 0.f, count = 0.f;
  for (int i = threadIdx.x; i < BATCH; i += 256) {
    float h = hp[i];
    uint nu = negmin[i], su = semimin[i];
    float snsq = (su != FMAX_BITS) ? __uint_as_float(su) : __uint_as_float(nu);
    if (h > 0.f && nu != FMAX_BITS) {
      total += fmaxf(h - sqrtf(snsq) + TMARGIN, 0.f);
      count += 1.f;
    }
  }
  #pragma unroll
  for (int off = 32; off; off >>= 1) {
    total += __shfl_xor(total, off);
    count += __shfl_xor(count, off);
  }
  __shared__ float st[4], sc[4];
  int w = threadIdx.x >> 6, lane = threadIdx.x & 63;
  if (lane == 0) { st[w] = total; sc[w] = count; }
  __syncthreads();
  if (threadIdx.x == 0) {
    float T = st[0] + st[1] + st[2] + st[3];
    float C = sc[0] + sc[1] + sc[2] + sc[3];
    out[0] = C > 0.f ? T / C : 0.f;
  }
}

extern "C" void kernel_launch(void* const* d_in, const int* in_sizes, int n_in,
                              void* d_out, int out_size, void* d_ws, size_t ws_size,
                              hipStream_t stream) {
  const float* emb  = (const float*)d_in[0];
  const int* labels = (const int*)d_in[1];
  float* out        = (float*)d_out;

  _Float16* eh  = (_Float16*)d_ws;                     // 2 MB
  _Float16* el  = eh + (size_t)BATCH * DIM;            // 2 MB
  float* norms  = (float*)(el + (size_t)BATCH * DIM);  // 32 KB
  float* hp     = norms + BATCH;                       // 32 KB
  uint* negmin  = (uint*)(hp + BATCH);                 // 32 KB
  uint* semimin = negmin + BATCH;                      // 32 KB
  int* counts   = (int*)(semimin + BATCH);             // 2 KB
  int* members  = counts + NCLS;                       // 256 KB

  hipMemsetAsync(counts, 0, NCLS * sizeof(int), stream);
  k_prep<<<BATCH / 4, 256, 0, stream>>>(emb, labels, eh, el, norms, negmin, semimin,
                                        counts, members);
  k_hp<<<NCLS, 256, 0, stream>>>(emb, norms, counts, members, hp);
  k_main<<<dim3(BATCH / 128, BATCH / 128), 256, 0, stream>>>(eh, el, labels, norms, hp,
                                                             negmin, semimin);
  k_final<<<1, 256, 0, stream>>>(hp, negmin, semimin, out);
}

// Round 4
// 155.780 us; speedup vs baseline: 2.5970x; 1.4305x over previous
//
#include <hip/hip_runtime.h>

typedef unsigned int uint;
typedef _Float16 half2v __attribute__((ext_vector_type(2)));
typedef _Float16 half8  __attribute__((ext_vector_type(8)));
typedef float    f32x4  __attribute__((ext_vector_type(4)));

#define BATCH   8192
#define DIM     128
#define NCLS    512
#define TMARGIN 0.3f
#define FMAX_BITS 0x7F7FFFFFu
#define BIGF 3.402823466e+38f
#define MAXM 128

// ---------- k_prep: norms + f16 hi/lo split + init mins + class scatter ------
__global__ __launch_bounds__(256) void k_prep(
    const float* __restrict__ emb, const int* __restrict__ labels,
    _Float16* __restrict__ eh, _Float16* __restrict__ el,
    float* __restrict__ norms, uint* __restrict__ negmin, uint* __restrict__ semimin,
    int* __restrict__ counts, int* __restrict__ members) {
  int w = threadIdx.x >> 6, lane = threadIdx.x & 63;
  int row = blockIdx.x * 4 + w;
  float2 v = reinterpret_cast<const float2*>(emb + (size_t)row * DIM)[lane];
  _Float16 h0 = (_Float16)v.x, h1 = (_Float16)v.y;
  half2v hv = {h0, h1};
  half2v lv = {(_Float16)(v.x - (float)h0), (_Float16)(v.y - (float)h1)};
  reinterpret_cast<half2v*>(eh + (size_t)row * DIM)[lane] = hv;
  reinterpret_cast<half2v*>(el + (size_t)row * DIM)[lane] = lv;
  float s = v.x * v.x + v.y * v.y;
  #pragma unroll
  for (int off = 32; off; off >>= 1) s += __shfl_xor(s, off);
  if (lane == 0) {
    norms[row]   = s;
    negmin[row]  = FMAX_BITS;
    semimin[row] = FMAX_BITS;
    int c = labels[row];
    int p = atomicAdd(&counts[c], 1);
    if (p < MAXM) members[c * MAXM + p] = row;
  }
}

// ---------- k_hp: hardest positive; b-loop parallel over 16-lane groups ------
__global__ __launch_bounds__(256) void k_hp(
    const float* __restrict__ emb, const float* __restrict__ norms,
    const int* __restrict__ counts, const int* __restrict__ members,
    float* __restrict__ hp) {
  int c = blockIdx.x;
  int m = counts[c]; if (m > MAXM) m = MAXM;
  int w = threadIdx.x >> 6, lane = threadIdx.x & 63;
  int g = lane >> 4, gl = lane & 15;
  for (int a = w; a < m; a += 4) {
    int i = members[c * MAXM + a];
    const float4* pi = reinterpret_cast<const float4*>(emb + (size_t)i * DIM + gl * 8);
    float4 xi0 = pi[0], xi1 = pi[1];
    float ni = norms[i];
    float best = 0.f;
    for (int b = g; b < m; b += 4) {
      if (b == a) continue;
      int j = members[c * MAXM + b];
      const float4* pj = reinterpret_cast<const float4*>(emb + (size_t)j * DIM + gl * 8);
      float4 xj0 = pj[0], xj1 = pj[1];
      float d = xi0.x*xj0.x + xi0.y*xj0.y + xi0.z*xj0.z + xi0.w*xj0.w
              + xi1.x*xj1.x + xi1.y*xj1.y + xi1.z*xj1.z + xi1.w*xj1.w;
      #pragma unroll
      for (int off = 1; off < 16; off <<= 1) d += __shfl_xor(d, off);
      float sq = fmaxf(ni + norms[j] - 2.f * d, 0.f);
      best = fmaxf(best, sq);
    }
    best = fmaxf(best, __shfl_xor(best, 16));
    best = fmaxf(best, __shfl_xor(best, 32));
    if (lane == 0) hp[i] = best > 0.f ? sqrtf(best) : 0.f;
  }
}

// ---------- k_main: single-stream 6-chunk MFMA Gram via gload_lds ------------
// 128x128 tile, 4 waves, wave 64x64 = 4x4 frags of 16x16x32 f16.
// Chunk table (A|B source, k-offset): [l0|h0][h0|h0][h0|l0][l1|h1][h1|h1][h1|l1]
//   = hh + hl + lh, only 8 panel stages. LDS: A 16KB @0, B 16KB @16384, linear
//   dest + slot^=(row&7) pre-swizzled GLOBAL source; reads undo the swizzle.
#define LDA_OFF 0
#define LDB_OFF 16384

__global__ __launch_bounds__(256) void k_main(
    const _Float16* __restrict__ eh, const _Float16* __restrict__ el,
    const int* __restrict__ labels, const float* __restrict__ norms,
    const float* __restrict__ hp,
    uint* __restrict__ negmin, uint* __restrict__ semimin) {
  // triangular decode: bx >= by
  int idx = blockIdx.x;
  int bx = (int)((sqrtf(8.0f * (float)idx + 1.0f) - 1.0f) * 0.5f);
  while ((bx + 1) * (bx + 2) / 2 <= idx) ++bx;
  while (bx * (bx + 1) / 2 > idx) --bx;
  int by = idx - bx * (bx + 1) / 2;

  __shared__ __align__(16) char lds[32768];
  const int t = threadIdx.x, lane = t & 63, w = t >> 6;
  const int wr = w >> 1, wc = w & 1;
  const int i0 = by * 128, j0 = bx * 128;
  const int r16 = lane & 15, kg = lane >> 4;

  // stage one 128x64-f16 panel (16 KB): wave-uniform LDS dest, swizzled g-src
  auto stage = [&](int lbase, const _Float16* src, int row0, int koff) {
    #pragma unroll
    for (int q = 0; q < 4; ++q) {
      int s = (w * 4 + q) * 64 + lane;           // 0..1023
      int row = s >> 3, slot = s & 7;
      int slotg = slot ^ (row & 7);
      const _Float16* gp = src + (size_t)(row0 + row) * DIM + koff + slotg * 8;
      char* lp = lds + lbase + (w * 4 + q) * 1024;   // uniform; HW adds lane*16
      __builtin_amdgcn_global_load_lds(
          (const __attribute__((address_space(1))) void*)gp,
          (__attribute__((address_space(3))) void*)lp, 16, 0, 0);
    }
  };

  f32x4 acc[4][4];
  #pragma unroll
  for (int m = 0; m < 4; ++m)
    #pragma unroll
    for (int n = 0; n < 4; ++n) acc[m][n] = (f32x4){0.f, 0.f, 0.f, 0.f};

  auto compute = [&]() {
    #pragma unroll
    for (int ks = 0; ks < 2; ++ks) {
      int slot = (ks * 4 + kg) ^ (r16 & 7);      // same for all m,n (row&7==r16&7)
      half8 a[4], b[4];
      #pragma unroll
      for (int m = 0; m < 4; ++m) {
        int row = wr * 64 + 16 * m + r16;
        a[m] = *reinterpret_cast<const half8*>(lds + LDA_OFF + row * 128 + slot * 16);
      }
      #pragma unroll
      for (int n = 0; n < 4; ++n) {
        int row = wc * 64 + 16 * n + r16;
        b[n] = *reinterpret_cast<const half8*>(lds + LDB_OFF + row * 128 + slot * 16);
      }
      #pragma unroll
      for (int m = 0; m < 4; ++m)
        #pragma unroll
        for (int n = 0; n < 4; ++n)
          acc[m][n] = __builtin_amdgcn_mfma_f32_16x16x32_f16(a[m], b[n], acc[m][n], 0, 0, 0);
    }
  };

  #define STEP(FIRST, SA, PA, SB, PB, KO)                         \
    {                                                             \
      if (!(FIRST)) __syncthreads();                              \
      if (SA) stage(LDA_OFF, PA, i0, KO);                         \
      if (SB) stage(LDB_OFF, PB, j0, KO);                         \
      asm volatile("s_waitcnt vmcnt(0)" ::: "memory");            \
      __syncthreads();                                            \
      compute();                                                  \
    }

  STEP(1, 1, el, 1, eh, 0)    // l0 | h0
  STEP(0, 1, eh, 0, eh, 0)    // h0 | h0
  STEP(0, 0, eh, 1, el, 0)    // h0 | l0
  STEP(0, 1, el, 1, eh, 64)   // l1 | h1
  STEP(0, 1, eh, 0, eh, 64)   // h1 | h1
  STEP(0, 0, eh, 1, el, 64)   // h1 | l1
  #undef STEP

  // ---- epilogue, squared-distance space. C/D: col=r16, row=4*kg+reg ----
  const int i0w = i0 + wr * 64, j0w = j0 + wc * 64;
  float nj[4], hsqj[4], hs2j[4];
  int lj[4];
  #pragma unroll
  for (int n = 0; n < 4; ++n) {
    int gj = j0w + 16 * n + r16;
    nj[n] = norms[gj];
    lj[n] = labels[gj];
    float hj = hp[gj];
    hsqj[n] = hj * hj;
    hs2j[n] = (hj + TMARGIN) * (hj + TMARGIN);
  }
  int liv[16];
  #pragma unroll
  for (int m = 0; m < 4; ++m) {
    #pragma unroll
    for (int q = 0; q < 4; ++q) {
      int gi = i0w + 16 * m + 4 * kg + q;
      float ni = norms[gi];
      int li = labels[gi];
      liv[m * 4 + q] = li;
      float h = hp[gi];
      float hsq = h * h, hs2 = (h + TMARGIN) * (h + TMARGIN);
      float rn = BIGF, rs = BIGF;
      #pragma unroll
      for (int n = 0; n < 4; ++n) {
        float sq = fmaxf(ni + nj[n] - 2.f * acc[m][n][q], 0.f);
        acc[m][n][q] = sq;              // keep for col pass
        if (li != lj[n]) {
          rn = fminf(rn, sq);
          if (sq > hsq && sq < hs2) rs = fminf(rs, sq);
        }
      }
      #pragma unroll
      for (int off = 1; off < 16; off <<= 1) {
        rn = fminf(rn, __shfl_xor(rn, off));
        rs = fminf(rs, __shfl_xor(rs, off));
      }
      if (r16 == 0) {
        atomicMin(negmin  + gi, __float_as_uint(rn));
        atomicMin(semimin + gi, __float_as_uint(rs));
      }
    }
  }
  if (bx != by) {                       // col pass: pairs (gj, gi)
    #pragma unroll
    for (int n = 0; n < 4; ++n) {
      float rn = BIGF, rs = BIGF;
      #pragma unroll
      for (int m = 0; m < 4; ++m)
        #pragma unroll
        for (int q = 0; q < 4; ++q) {
          float sq = acc[m][n][q];
          if (liv[m * 4 + q] != lj[n]) {
            rn = fminf(rn, sq);
            if (sq > hsqj[n] && sq < hs2j[n]) rs = fminf(rs, sq);
          }
        }
      rn = fminf(rn, __shfl_xor(rn, 16));
      rs = fminf(rs, __shfl_xor(rs, 16));
      rn = fminf(rn, __shfl_xor(rn, 32));
      rs = fminf(rs, __shfl_xor(rs, 32));
      if (kg == 0) {
        int gj = j0w + 16 * n + r16;
        atomicMin(negmin  + gj, __float_as_uint(rn));
        atomicMin(semimin + gj, __float_as_uint(rs));
      }
    }
  }
}

// ---------- k_final ------------------------------------------------------------
__global__ __launch_bounds__(256) void k_final(
    const float* __restrict__ hp, const uint* __restrict__ negmin,
    const uint* __restrict__ semimin, float* __restrict__ out) {
  float total = 0.f, count = 0.f;
  for (int i = threadIdx.x; i < BATCH; i += 256) {
    float h = hp[i];
    uint nu = negmin[i], su = semimin[i];
    float snsq = (su != FMAX_BITS) ? __uint_as_float(su) : __uint_as_float(nu);
    if (h > 0.f && nu != FMAX_BITS) {
      total += fmaxf(h - sqrtf(snsq) + TMARGIN, 0.f);
      count += 1.f;
    }
  }
  #pragma unroll
  for (int off = 32; off; off >>= 1) {
    total += __shfl_xor(total, off);
    count += __shfl_xor(count, off);
  }
  __shared__ float st[4], sc[4];
  int w = threadIdx.x >> 6, lane = threadIdx.x & 63;
  if (lane == 0) { st[w] = total; sc[w] = count; }
  __syncthreads();
  if (threadIdx.x == 0) {
    float T = st[0] + st[1] + st[2] + st[3];
    float C = sc[0] + sc[1] + sc[2] + sc[3];
    out[0] = C > 0.f ? T / C : 0.f;
  }
}

extern "C" void kernel_launch(void* const* d_in, const int* in_sizes, int n_in,
                              void* d_out, int out_size, void* d_ws, size_t ws_size,
                              hipStream_t stream) {
  const float* emb  = (const float*)d_in[0];
  const int* labels = (const int*)d_in[1];
  float* out        = (float*)d_out;

  _Float16* eh  = (_Float16*)d_ws;                     // 2 MB
  _Float16* el  = eh + (size_t)BATCH * DIM;            // 2 MB
  float* norms  = (float*)(el + (size_t)BATCH * DIM);  // 32 KB
  float* hp     = norms + BATCH;                       // 32 KB
  uint* negmin  = (uint*)(hp + BATCH);                 // 32 KB
  uint* semimin = negmin + BATCH;                      // 32 KB
  int* counts   = (int*)(semimin + BATCH);             // 2 KB
  int* members  = counts + NCLS;                       // 256 KB

  hipMemsetAsync(counts, 0, NCLS * sizeof(int), stream);
  k_prep<<<BATCH / 4, 256, 0, stream>>>(emb, labels, eh, el, norms, negmin, semimin,
                                        counts, members);
  k_hp<<<NCLS, 256, 0, stream>>>(emb, norms, counts, members, hp);
  const int ntri = (BATCH / 128) * (BATCH / 128 + 1) / 2;   // 2080
  k_main<<<ntri, 256, 0, stream>>>(eh, el, labels, norms, hp, negmin, semimin);
  k_final<<<1, 256, 0, stream>>>(hp, negmin, semimin, out);
}

// Round 5
// 154.988 us; speedup vs baseline: 2.6102x; 1.0051x over previous
//
#include <hip/hip_runtime.h>

typedef unsigned int uint;
typedef _Float16 half2v __attribute__((ext_vector_type(2)));
typedef _Float16 half8  __attribute__((ext_vector_type(8)));
typedef float    f32x4  __attribute__((ext_vector_type(4)));

#define BATCH   8192
#define DIM     128
#define NCLS    512
#define TMARGIN 0.3f
#define BIGF    3.402823466e+38f
#define MAXM    128
#define SEGS    8
#define TPB     8     // j-tiles (128 cols) per block

// ---------- k_prep: norms + f16 hi/lo split + class scatter ------------------
__global__ __launch_bounds__(256) void k_prep(
    const float* __restrict__ emb, const int* __restrict__ labels,
    _Float16* __restrict__ eh, _Float16* __restrict__ el,
    float* __restrict__ norms, int* __restrict__ counts, int* __restrict__ members) {
  int w = threadIdx.x >> 6, lane = threadIdx.x & 63;
  int row = blockIdx.x * 4 + w;
  float2 v = reinterpret_cast<const float2*>(emb + (size_t)row * DIM)[lane];
  _Float16 h0 = (_Float16)v.x, h1 = (_Float16)v.y;
  half2v hv = {h0, h1};
  half2v lv = {(_Float16)(v.x - (float)h0), (_Float16)(v.y - (float)h1)};
  reinterpret_cast<half2v*>(eh + (size_t)row * DIM)[lane] = hv;
  reinterpret_cast<half2v*>(el + (size_t)row * DIM)[lane] = lv;
  float s = v.x * v.x + v.y * v.y;
  #pragma unroll
  for (int off = 32; off; off >>= 1) s += __shfl_xor(s, off);
  if (lane == 0) {
    norms[row] = s;
    int c = labels[row];
    int p = atomicAdd(&counts[c], 1);
    if (p < MAXM) members[c * MAXM + p] = row;
  }
}

// ---------- k_hp: hardest positive per row (squared -> sqrt) -----------------
__global__ __launch_bounds__(256) void k_hp(
    const float* __restrict__ emb, const float* __restrict__ norms,
    const int* __restrict__ counts, const int* __restrict__ members,
    float* __restrict__ hp) {
  int c = blockIdx.x;
  int m = counts[c]; if (m > MAXM) m = MAXM;
  int w = threadIdx.x >> 6, lane = threadIdx.x & 63;
  int g = lane >> 4, gl = lane & 15;
  for (int a = w; a < m; a += 4) {
    int i = members[c * MAXM + a];
    const float4* pi = reinterpret_cast<const float4*>(emb + (size_t)i * DIM + gl * 8);
    float4 xi0 = pi[0], xi1 = pi[1];
    float ni = norms[i];
    float best = 0.f;
    for (int b = g; b < m; b += 4) {
      if (b == a) continue;
      int j = members[c * MAXM + b];
      const float4* pj = reinterpret_cast<const float4*>(emb + (size_t)j * DIM + gl * 8);
      float4 xj0 = pj[0], xj1 = pj[1];
      float d = xi0.x*xj0.x + xi0.y*xj0.y + xi0.z*xj0.z + xi0.w*xj0.w
              + xi1.x*xj1.x + xi1.y*xj1.y + xi1.z*xj1.z + xi1.w*xj1.w;
      #pragma unroll
      for (int off = 1; off < 16; off <<= 1) d += __shfl_xor(d, off);
      float sq = fmaxf(ni + norms[j] - 2.f * d, 0.f);
      best = fmaxf(best, sq);
    }
    best = fmaxf(best, __shfl_xor(best, 16));
    best = fmaxf(best, __shfl_xor(best, 32));
    if (lane == 0) hp[i] = best > 0.f ? sqrtf(best) : 0.f;
  }
}

// ---------- k_main: row-panel sweep, A in regs, B dbuf LDS, no atomics -------
// block = (seg, panel). 4 waves x 32 rows. Per tile: 2 K-half phases.
// t-space epilogue: t = 2*dot - nj; rmax = max masked t (neg_min),
// smax = max masked t with t < c2 (= ni - hp^2)  (semi window upper bound
// checked here, lower bound checked in k_final).
__global__ __launch_bounds__(256, 2) void k_main(
    const _Float16* __restrict__ eh, const _Float16* __restrict__ el,
    const int* __restrict__ labels, const float* __restrict__ norms,
    const float* __restrict__ hp, float* __restrict__ rowres) {
  __shared__ __align__(16) char lds[65536];   // 2 bufs x (Bh 16KB + Bl 16KB)
  const int t = threadIdx.x, lane = t & 63, w = t >> 6;
  const int r16 = lane & 15, kg = lane >> 4;
  const int by = blockIdx.y, seg = blockIdx.x;
  const int i0 = by * 128;
  const int jseg = seg * (TPB * 128);
  const int sgl = ((t & 7) ^ ((t >> 3) & 7)) * 8;   // swizzled source slot

  // per-lane row constants (8 rows per lane)
  float c2[2][4], rmax[2][4], smax[2][4];
  int li[2][4];
  #pragma unroll
  for (int m = 0; m < 2; ++m)
    #pragma unroll
    for (int q = 0; q < 4; ++q) {
      int gi = i0 + 32 * w + 16 * m + 4 * kg + q;
      float ni = norms[gi], h = hp[gi];
      c2[m][q] = ni - h * h;
      li[m][q] = labels[gi];
      rmax[m][q] = -BIGF;
      smax[m][q] = -BIGF;
    }

  // A fragments in registers: full K, hi+lo
  half8 ah[2][4], al[2][4];
  #pragma unroll
  for (int m = 0; m < 2; ++m) {
    size_t rbase = (size_t)(i0 + 32 * w + 16 * m + r16) * DIM + kg * 8;
    #pragma unroll
    for (int ks = 0; ks < 4; ++ks) {
      ah[m][ks] = *reinterpret_cast<const half8*>(eh + rbase + ks * 32);
      al[m][ks] = *reinterpret_cast<const half8*>(el + rbase + ks * 32);
    }
  }

  f32x4 acc[2][8];
  #pragma unroll
  for (int m = 0; m < 2; ++m)
    #pragma unroll
    for (int n = 0; n < 8; ++n) acc[m][n] = (f32x4){0.f, 0.f, 0.f, 0.f};

  // stage one K-half of a B tile (Bh+Bl, 32KB) into buf C
  #define STAGE(J0T, KH, C)                                                    \
    {                                                                          \
      const _Float16* hb = eh + (size_t)((J0T) + (t >> 3)) * DIM + (KH)*64 + sgl; \
      const _Float16* lb = el + (size_t)((J0T) + (t >> 3)) * DIM + (KH)*64 + sgl; \
      _Pragma("unroll") for (int q = 0; q < 8; ++q) {                          \
        const _Float16* gp = (q < 4 ? hb : lb) + (q & 3) * 4096;               \
        char* lp = lds + (C)*32768 + (q >> 2) * 16384 + (q & 3) * 4096 + w * 1024; \
        __builtin_amdgcn_global_load_lds(                                      \
            (const __attribute__((address_space(1))) void*)gp,                 \
            (__attribute__((address_space(3))) void*)lp, 16, 0, 0);            \
      }                                                                        \
    }

  #define COMPUTE(KH, C)                                                       \
    {                                                                          \
      const char* pb = lds + (C)*32768 + r16 * 128;                            \
      _Pragma("unroll") for (int ks2 = 0; ks2 < 2; ++ks2) {                    \
        int so = ((ks2 * 4 + kg) ^ (r16 & 7)) * 16;                            \
        _Pragma("unroll") for (int n = 0; n < 8; ++n) {                        \
          half8 bh = *reinterpret_cast<const half8*>(pb + n * 2048 + so);      \
          half8 bl = *reinterpret_cast<const half8*>(pb + 16384 + n * 2048 + so); \
          _Pragma("unroll") for (int m = 0; m < 2; ++m) {                      \
            acc[m][n] = __builtin_amdgcn_mfma_f32_16x16x32_f16(                \
                ah[m][(KH)*2 + ks2], bh, acc[m][n], 0, 0, 0);                  \
            acc[m][n] = __builtin_amdgcn_mfma_f32_16x16x32_f16(                \
                al[m][(KH)*2 + ks2], bh, acc[m][n], 0, 0, 0);                  \
            acc[m][n] = __builtin_amdgcn_mfma_f32_16x16x32_f16(                \
                ah[m][(KH)*2 + ks2], bl, acc[m][n], 0, 0, 0);                  \
          }                                                                    \
        }                                                                      \
      }                                                                        \
    }

  STAGE(jseg, 0, 0);        // prologue: tile 0, K-half 0 -> buf0
  __syncthreads();

  for (int jt = 0; jt < TPB; ++jt) {
    const int j0t = jseg + jt * 128;
    // prefetch per-tile col constants (used in epilogue)
    float njv[8];
    int ljv[8];
    #pragma unroll
    for (int n = 0; n < 8; ++n) {
      int gj = j0t + 16 * n + r16;
      njv[n] = norms[gj];
      ljv[n] = labels[gj];
    }
    // phase kh=0: compute buf0, stage this tile's kh=1 -> buf1
    STAGE(j0t, 1, 1);
    COMPUTE(0, 0);
    __syncthreads();
    // phase kh=1: compute buf1, stage next tile's kh=0 -> buf0
    if (jt + 1 < TPB) STAGE(j0t + 128, 0, 0);
    COMPUTE(1, 1);

    // tile epilogue: register-only masked max in t-space
    #pragma unroll
    for (int n = 0; n < 8; ++n)
      #pragma unroll
      for (int m = 0; m < 2; ++m)
        #pragma unroll
        for (int q = 0; q < 4; ++q) {
          float tv = fmaf(2.f, acc[m][n][q], -njv[n]);
          float tm = (li[m][q] != ljv[n]) ? tv : -BIGF;
          rmax[m][q] = fmaxf(rmax[m][q], tm);
          float tl = (tm < c2[m][q]) ? tm : -BIGF;
          smax[m][q] = fmaxf(smax[m][q], tl);
          acc[m][n][q] = 0.f;
        }
    __syncthreads();
  }
  #undef STAGE
  #undef COMPUTE

  // block end: reduce over the 16 col-lanes, write per-segment row results
  #pragma unroll
  for (int m = 0; m < 2; ++m)
    #pragma unroll
    for (int q = 0; q < 4; ++q) {
      float r = rmax[m][q], s = smax[m][q];
      #pragma unroll
      for (int off = 1; off < 16; off <<= 1) {
        r = fmaxf(r, __shfl_xor(r, off));
        s = fmaxf(s, __shfl_xor(s, off));
      }
      if (r16 == 0) {
        int row = i0 + 32 * w + 16 * m + 4 * kg + q;
        float2* pp = reinterpret_cast<float2*>(rowres);
        pp[row * SEGS + seg] = make_float2(r, s);
      }
    }
}

// ---------- k_final: combine segments, finalize scalar -----------------------
__global__ __launch_bounds__(256) void k_final(
    const float* __restrict__ norms, const float* __restrict__ hp,
    const float* __restrict__ rowres, float* __restrict__ out) {
  const float2* pp = reinterpret_cast<const float2*>(rowres);
  float total = 0.f, count = 0.f;
  for (int i = threadIdx.x; i < BATCH; i += 256) {
    float rmax = -BIGF, smax = -BIGF;
    #pragma unroll
    for (int s = 0; s < SEGS; ++s) {
      float2 v = pp[i * SEGS + s];
      rmax = fmaxf(rmax, v.x);
      smax = fmaxf(smax, v.y);
    }
    float ni = norms[i], h = hp[i];
    float c1 = ni - (h + TMARGIN) * (h + TMARGIN);
    bool has_neg = rmax > -1e37f;
    float neg_sq  = fmaxf(ni - rmax, 0.f);
    float semi_sq = (smax > c1) ? fmaxf(ni - smax, 0.f) : neg_sq;
    if (h > 0.f && has_neg) {
      total += fmaxf(h - sqrtf(semi_sq) + TMARGIN, 0.f);
      count += 1.f;
    }
  }
  #pragma unroll
  for (int off = 32; off; off >>= 1) {
    total += __shfl_xor(total, off);
    count += __shfl_xor(count, off);
  }
  __shared__ float st[4], sc[4];
  int w = threadIdx.x >> 6, lane = threadIdx.x & 63;
  if (lane == 0) { st[w] = total; sc[w] = count; }
  __syncthreads();
  if (threadIdx.x == 0) {
    float T = st[0] + st[1] + st[2] + st[3];
    float C = sc[0] + sc[1] + sc[2] + sc[3];
    out[0] = C > 0.f ? T / C : 0.f;
  }
}

extern "C" void kernel_launch(void* const* d_in, const int* in_sizes, int n_in,
                              void* d_out, int out_size, void* d_ws, size_t ws_size,
                              hipStream_t stream) {
  const float* emb  = (const float*)d_in[0];
  const int* labels = (const int*)d_in[1];
  float* out        = (float*)d_out;

  _Float16* eh  = (_Float16*)d_ws;                     // 2 MB
  _Float16* el  = eh + (size_t)BATCH * DIM;            // 2 MB
  float* norms  = (float*)(el + (size_t)BATCH * DIM);  // 32 KB
  float* hp     = norms + BATCH;                       // 32 KB
  int* counts   = (int*)(hp + BATCH);                  // 2 KB
  int* members  = counts + NCLS;                       // 256 KB
  float* rowres = (float*)(members + NCLS * MAXM);     // 512 KB

  hipMemsetAsync(counts, 0, NCLS * sizeof(int), stream);
  k_prep<<<BATCH / 4, 256, 0, stream>>>(emb, labels, eh, el, norms, counts, members);
  k_hp<<<NCLS, 256, 0, stream>>>(emb, norms, counts, members, hp);
  k_main<<<dim3(SEGS, BATCH / 128), 256, 0, stream>>>(eh, el, labels, norms, hp, rowres);
  k_final<<<1, 256, 0, stream>>>(norms, hp, rowres, out);
}

// Round 6
// 109.872 us; speedup vs baseline: 3.6820x; 1.4106x over previous
//
#include <hip/hip_runtime.h>

typedef unsigned int uint;
typedef _Float16 half2v __attribute__((ext_vector_type(2)));
typedef _Float16 half8  __attribute__((ext_vector_type(8)));
typedef float    f32x4  __attribute__((ext_vector_type(4)));

#define BATCH   8192
#define DIM     128
#define NCLS    512
#define TMARGIN 0.3f
#define BIGF    3.402823466e+38f
#define MAXM    128
#define NPAN    64
#define NSLOT   64

// ---------- k_prep: norms + f16 hi/lo split + class scatter ------------------
__global__ __launch_bounds__(256) void k_prep(
    const float* __restrict__ emb, const int* __restrict__ labels,
    _Float16* __restrict__ eh, _Float16* __restrict__ el,
    float* __restrict__ norms, int* __restrict__ counts, int* __restrict__ members) {
  int w = threadIdx.x >> 6, lane = threadIdx.x & 63;
  int row = blockIdx.x * 4 + w;
  float2 v = reinterpret_cast<const float2*>(emb + (size_t)row * DIM)[lane];
  _Float16 h0 = (_Float16)v.x, h1 = (_Float16)v.y;
  half2v hv = {h0, h1};
  half2v lv = {(_Float16)(v.x - (float)h0), (_Float16)(v.y - (float)h1)};
  reinterpret_cast<half2v*>(eh + (size_t)row * DIM)[lane] = hv;
  reinterpret_cast<half2v*>(el + (size_t)row * DIM)[lane] = lv;
  float s = v.x * v.x + v.y * v.y;
  #pragma unroll
  for (int off = 32; off; off >>= 1) s += __shfl_xor(s, off);
  if (lane == 0) {
    norms[row] = s;
    int c = labels[row];
    int p = atomicAdd(&counts[c], 1);
    if (p < MAXM) members[c * MAXM + p] = row;
  }
}

// ---------- k_hp: hardest positive per row (squared -> sqrt) -----------------
__global__ __launch_bounds__(256) void k_hp(
    const float* __restrict__ emb, const float* __restrict__ norms,
    const int* __restrict__ counts, const int* __restrict__ members,
    float* __restrict__ hp) {
  int c = blockIdx.x;
  int m = counts[c]; if (m > MAXM) m = MAXM;
  int w = threadIdx.x >> 6, lane = threadIdx.x & 63;
  int g = lane >> 4, gl = lane & 15;
  for (int a = w; a < m; a += 4) {
    int i = members[c * MAXM + a];
    const float4* pi = reinterpret_cast<const float4*>(emb + (size_t)i * DIM + gl * 8);
    float4 xi0 = pi[0], xi1 = pi[1];
    float ni = norms[i];
    float best = 0.f;
    for (int b = g; b < m; b += 4) {
      if (b == a) continue;
      int j = members[c * MAXM + b];
      const float4* pj = reinterpret_cast<const float4*>(emb + (size_t)j * DIM + gl * 8);
      float4 xj0 = pj[0], xj1 = pj[1];
      float d = xi0.x*xj0.x + xi0.y*xj0.y + xi0.z*xj0.z + xi0.w*xj0.w
              + xi1.x*xj1.x + xi1.y*xj1.y + xi1.z*xj1.z + xi1.w*xj1.w;
      #pragma unroll
      for (int off = 1; off < 16; off <<= 1) d += __shfl_xor(d, off);
      float sq = fmaxf(ni + norms[j] - 2.f * d, 0.f);
      best = fmaxf(best, sq);
    }
    best = fmaxf(best, __shfl_xor(best, 16));
    best = fmaxf(best, __shfl_xor(best, 32));
    if (lane == 0) hp[i] = best > 0.f ? sqrtf(best) : 0.f;
  }
}

// ---------- k_main: symmetric-triangle 128x128 tile, row+col passes ----------
// block (pi,pj), pj>=pi. A = panel pi rows (regs, full K); B = panel pj cols
// staged in K-quarters (16KB, dbuf, kg-major layout, conflict-free ds_read).
// Row-pass: t = 2dot - nj, running max -> rowres[row of pi][slot pj].
// Col-pass (pi!=pj): t_col = 2dot - ni -> rowres[col of pj][slot pi].
__global__ __launch_bounds__(256, 2) void k_main(
    const _Float16* __restrict__ eh, const _Float16* __restrict__ el,
    const int* __restrict__ labels, const float* __restrict__ norms,
    const float* __restrict__ hp, float* __restrict__ rowres) {
  int idx = blockIdx.x;
  int bx = (int)((sqrtf(8.0f * (float)idx + 1.0f) - 1.0f) * 0.5f);
  while ((bx + 1) * (bx + 2) / 2 <= idx) ++bx;
  while (bx * (bx + 1) / 2 > idx) --bx;
  const int pi = idx - bx * (bx + 1) / 2;   // row panel
  const int pj = bx;                        // col panel (pj >= pi)
  const int i0 = pi * 128, j0 = pj * 128;

  __shared__ __align__(16) char lds[32768];
  const int t = threadIdx.x, lane = t & 63, w = t >> 6;
  const int r16 = lane & 15, kg = lane >> 4;

  // stage one K-quarter (k = kq*32..+32) of B panel (h+l, 16KB) into buf C.
  // LDS 16B-unit layout: hl*512 + kslot*128 + col ; linear dest, per-lane src.
  #define STAGE(KQ, C)                                                        \
    {                                                                         \
      _Pragma("unroll") for (int it = 0; it < 4; ++it) {                      \
        const _Float16* sb = (it < 2) ? eh : el;                              \
        int kslot = (it * 2 + (t >> 7)) & 3;                                  \
        const _Float16* gp = sb + (size_t)(j0 + (t & 127)) * DIM              \
                             + (KQ) * 32 + kslot * 8;                         \
        char* lp = lds + (C) * 16384 + it * 4096 + (t >> 6) * 1024;           \
        __builtin_amdgcn_global_load_lds(                                     \
            (const __attribute__((address_space(1))) void*)gp,                \
            (__attribute__((address_space(3))) void*)lp, 16, 0, 0);           \
      }                                                                       \
    }

  // A fragments: rows i0 + 32w + 16m + r16, full K in quarters
  half8 ah[2][4], al[2][4];
  #pragma unroll
  for (int m = 0; m < 2; ++m) {
    size_t rbase = (size_t)(i0 + 32 * w + 16 * m + r16) * DIM + kg * 8;
    #pragma unroll
    for (int ks = 0; ks < 4; ++ks) {
      ah[m][ks] = *reinterpret_cast<const half8*>(eh + rbase + ks * 32);
      al[m][ks] = *reinterpret_cast<const half8*>(el + rbase + ks * 32);
    }
  }

  // row constants
  float ni_[2][4], c2[2][4], rmax[2][4], smax[2][4];
  int li[2][4];
  #pragma unroll
  for (int m = 0; m < 2; ++m)
    #pragma unroll
    for (int q = 0; q < 4; ++q) {
      int gi = i0 + 32 * w + 16 * m + 4 * kg + q;
      float nv = norms[gi], h = hp[gi];
      ni_[m][q] = nv;
      c2[m][q]  = nv - h * h;
      li[m][q]  = labels[gi];
      rmax[m][q] = -BIGF;
      smax[m][q] = -BIGF;
    }
  // col constants
  float njv[8], c2j[8];
  int ljv[8];
  #pragma unroll
  for (int n = 0; n < 8; ++n) {
    int gj = j0 + 16 * n + r16;
    float nv = norms[gj], hj = hp[gj];
    njv[n] = nv;
    c2j[n] = nv - hj * hj;
    ljv[n] = labels[gj];
  }

  f32x4 acc[2][8];
  #pragma unroll
  for (int m = 0; m < 2; ++m)
    #pragma unroll
    for (int n = 0; n < 8; ++n) acc[m][n] = (f32x4){0.f, 0.f, 0.f, 0.f};

  STAGE(0, 0);
  __syncthreads();
  #pragma unroll
  for (int kq = 0; kq < 4; ++kq) {
    if (kq < 3) STAGE(kq + 1, (kq + 1) & 1);
    __builtin_amdgcn_s_setprio(1);
    #pragma unroll
    for (int n = 0; n < 8; ++n) {
      const char* pb = lds + (kq & 1) * 16384 + kg * 2048 + (16 * n + r16) * 16;
      half8 bh = *reinterpret_cast<const half8*>(pb);
      half8 bl = *reinterpret_cast<const half8*>(pb + 8192);
      #pragma unroll
      for (int m = 0; m < 2; ++m) {
        acc[m][n] = __builtin_amdgcn_mfma_f32_16x16x32_f16(ah[m][kq], bh, acc[m][n], 0, 0, 0);
        acc[m][n] = __builtin_amdgcn_mfma_f32_16x16x32_f16(al[m][kq], bh, acc[m][n], 0, 0, 0);
        acc[m][n] = __builtin_amdgcn_mfma_f32_16x16x32_f16(ah[m][kq], bl, acc[m][n], 0, 0, 0);
      }
    }
    __builtin_amdgcn_s_setprio(0);
    if (kq < 3) __syncthreads();
  }
  #undef STAGE

  // ---- epilogue: row + col masked running max in t-space ----
  // C/D layout: col = r16, row = 4*kg + reg(q)
  float crmax[8], csmax[8];
  #pragma unroll
  for (int n = 0; n < 8; ++n) { crmax[n] = -BIGF; csmax[n] = -BIGF; }
  #pragma unroll
  for (int m = 0; m < 2; ++m)
    #pragma unroll
    for (int q = 0; q < 4; ++q)
      #pragma unroll
      for (int n = 0; n < 8; ++n) {
        float d2 = acc[m][n][q] + acc[m][n][q];
        bool diff = (li[m][q] != ljv[n]);
        float tr = d2 - njv[n];
        float trm = diff ? tr : -BIGF;
        rmax[m][q] = fmaxf(rmax[m][q], trm);
        smax[m][q] = fmaxf(smax[m][q], (trm < c2[m][q]) ? trm : -BIGF);
        float tc = d2 - ni_[m][q];
        float tcm = diff ? tc : -BIGF;
        crmax[n] = fmaxf(crmax[n], tcm);
        csmax[n] = fmaxf(csmax[n], (tcm < c2j[n]) ? tcm : -BIGF);
      }

  float2* pp = reinterpret_cast<float2*>(rowres);
  // row pass: reduce over the 16 col-lanes (r16), write slot pj
  #pragma unroll
  for (int m = 0; m < 2; ++m)
    #pragma unroll
    for (int q = 0; q < 4; ++q) {
      float r = rmax[m][q], s = smax[m][q];
      #pragma unroll
      for (int off = 1; off < 16; off <<= 1) {
        r = fmaxf(r, __shfl_xor(r, off));
        s = fmaxf(s, __shfl_xor(s, off));
      }
      if (r16 == 0) {
        int gi = i0 + 32 * w + 16 * m + 4 * kg + q;
        pp[(size_t)gi * NSLOT + pj] = make_float2(r, s);
      }
    }
  // col pass: reduce over kg lanes, write slot pi (skip diagonal)
  if (pi != pj) {
    #pragma unroll
    for (int n = 0; n < 8; ++n) {
      float r = crmax[n], s = csmax[n];
      r = fmaxf(r, __shfl_xor(r, 16));
      s = fmaxf(s, __shfl_xor(s, 16));
      r = fmaxf(r, __shfl_xor(r, 32));
      s = fmaxf(s, __shfl_xor(s, 32));
      if (kg == 0) {
        int gj = j0 + 16 * n + r16;
        // NOTE: each wave covers only rows 32w..32w+31 of pi, so 4 waves
        // produce 4 partial col-maxes; combine via per-wave slot then max in
        // k_red would need 4 slots. Instead: stagger slots by wave and let
        // k_red's 64-slot max absorb it -- but slots are unique per block.
        // Resolve: reduce across waves through LDS (reuse staging buffer).
        reinterpret_cast<float2*>(lds)[(w * 8 + n) * 16 + r16] = make_float2(r, s);
      }
    }
    __syncthreads();
    // wave 0 merges the 4 per-wave col partials and writes
    if (w == 0) {
      #pragma unroll
      for (int n = 0; n < 8; ++n) {
        if (kg == 0) {
          float2 v0 = reinterpret_cast<float2*>(lds)[(0 * 8 + n) * 16 + r16];
          float2 v1 = reinterpret_cast<float2*>(lds)[(1 * 8 + n) * 16 + r16];
          float2 v2 = reinterpret_cast<float2*>(lds)[(2 * 8 + n) * 16 + r16];
          float2 v3 = reinterpret_cast<float2*>(lds)[(3 * 8 + n) * 16 + r16];
          float r = fmaxf(fmaxf(v0.x, v1.x), fmaxf(v2.x, v3.x));
          float s = fmaxf(fmaxf(v0.y, v1.y), fmaxf(v2.y, v3.y));
          int gj = j0 + 16 * n + r16;
          pp[(size_t)gj * NSLOT + pi] = make_float2(r, s);
        }
      }
    }
  }
}

// ---------- k_red: per-row combine of 64 slots -> per-block partial ----------
__global__ __launch_bounds__(256) void k_red(
    const float* __restrict__ norms, const float* __restrict__ hp,
    const float* __restrict__ rowres, float* __restrict__ partial) {
  int gt = blockIdx.x * 256 + threadIdx.x;   // 32768 threads, 4 per row
  int row = gt >> 2, q = gt & 3;
  const float2* pp = reinterpret_cast<const float2*>(rowres) + (size_t)row * NSLOT + q * 16;
  float rmax = -BIGF, smax = -BIGF;
  #pragma unroll
  for (int s = 0; s < 16; ++s) {
    float2 v = pp[s];
    rmax = fmaxf(rmax, v.x);
    smax = fmaxf(smax, v.y);
  }
  rmax = fmaxf(rmax, __shfl_xor(rmax, 1));
  smax = fmaxf(smax, __shfl_xor(smax, 1));
  rmax = fmaxf(rmax, __shfl_xor(rmax, 2));
  smax = fmaxf(smax, __shfl_xor(smax, 2));
  float total = 0.f, count = 0.f;
  if (q == 0) {
    float ni = norms[row], h = hp[row];
    float c1 = ni - (h + TMARGIN) * (h + TMARGIN);
    bool has_neg = rmax > -1e37f;
    float neg_sq  = fmaxf(ni - rmax, 0.f);
    float semi_sq = (smax > c1) ? fmaxf(ni - smax, 0.f) : neg_sq;
    if (h > 0.f && has_neg) {
      total = fmaxf(h - sqrtf(semi_sq) + TMARGIN, 0.f);
      count = 1.f;
    }
  }
  #pragma unroll
  for (int off = 32; off; off >>= 1) {
    total += __shfl_xor(total, off);
    count += __shfl_xor(count, off);
  }
  __shared__ float st[4], sc[4];
  int w = threadIdx.x >> 6, lane = threadIdx.x & 63;
  if (lane == 0) { st[w] = total; sc[w] = count; }
  __syncthreads();
  if (threadIdx.x == 0) {
    float2* po = reinterpret_cast<float2*>(partial);
    po[blockIdx.x] = make_float2(st[0] + st[1] + st[2] + st[3],
                                 sc[0] + sc[1] + sc[2] + sc[3]);
  }
}

// ---------- k_out: final scalar ----------------------------------------------
__global__ void k_out(const float* __restrict__ partial, float* __restrict__ out) {
  const float2* pp = reinterpret_cast<const float2*>(partial);
  int lane = threadIdx.x;
  float2 a = pp[lane], b = pp[lane + 64];
  float T = a.x + b.x, C = a.y + b.y;
  #pragma unroll
  for (int off = 32; off; off >>= 1) {
    T += __shfl_xor(T, off);
    C += __shfl_xor(C, off);
  }
  if (lane == 0) out[0] = C > 0.f ? T / C : 0.f;
}

extern "C" void kernel_launch(void* const* d_in, const int* in_sizes, int n_in,
                              void* d_out, int out_size, void* d_ws, size_t ws_size,
                              hipStream_t stream) {
  const float* emb  = (const float*)d_in[0];
  const int* labels = (const int*)d_in[1];
  float* out        = (float*)d_out;

  _Float16* eh  = (_Float16*)d_ws;                     // 2 MB
  _Float16* el  = eh + (size_t)BATCH * DIM;            // 2 MB
  float* norms  = (float*)(el + (size_t)BATCH * DIM);  // 32 KB
  float* hp     = norms + BATCH;                       // 32 KB
  int* counts   = (int*)(hp + BATCH);                  // 2 KB
  int* members  = counts + NCLS;                       // 256 KB
  float* rowres = (float*)(members + NCLS * MAXM);     // 4 MB
  float* partial = rowres + (size_t)BATCH * NSLOT * 2; // 1 KB

  hipMemsetAsync(counts, 0, NCLS * sizeof(int), stream);
  k_prep<<<BATCH / 4, 256, 0, stream>>>(emb, labels, eh, el, norms, counts, members);
  k_hp<<<NCLS, 256, 0, stream>>>(emb, norms, counts, members, hp);
  const int ntri = NPAN * (NPAN + 1) / 2;   // 2080
  k_main<<<ntri, 256, 0, stream>>>(eh, el, labels, norms, hp, rowres);
  k_red<<<BATCH * 4 / 256, 256, 0, stream>>>(norms, hp, rowres, partial);
  k_out<<<1, 64, 0, stream>>>(partial, out);
}